// Round 1
// baseline (142.760 us; speedup 1.0000x reference)
//
#include <hip/hip_runtime.h>

#define EXTENT 7
#define CHANNELS 256

// One block per (box, gy). 256 threads: lane groups of 64 cover the 256
// channels as float4; gx covered by t>>6 across two loop iterations
// (7*64 = 448 tasks over 256 threads).
__global__ __launch_bounds__(256) void roi_align_pyramid_kernel(
    const float* __restrict__ metadata,
    const float* __restrict__ boxes,
    const float* __restrict__ p2,
    const float* __restrict__ p3,
    const float* __restrict__ p4,
    const float* __restrict__ p5,
    float* __restrict__ out)
{
    const int blk = blockIdx.x;
    const int box = blk / EXTENT;
    const int gy  = blk % EXTENT;
    const int tid = threadIdx.x;

    const float rows = metadata[0];
    const float cols = metadata[1];

    const float x1 = boxes[box * 4 + 0];
    const float y1 = boxes[box * 4 + 1];
    const float x2 = boxes[box * 4 + 2];
    const float y2 = boxes[box * 4 + 3];

    // Level selection — replicate reference fp32 math.
    const float h = y2 - y1;
    const float w = x2 - x1;
    float roi_level = logf(sqrtf(h * w) / sqrtf(rows * cols)) / logf(2.0f);
    roi_level = fminf(5.0f, fmaxf(2.0f, 4.0f + rintf(roi_level)));
    const int lvl = (int)roi_level;  // 2..5

    const float* feat;
    int H;
    if      (lvl == 2) { feat = p2; H = 256; }
    else if (lvl == 3) { feat = p3; H = 128; }
    else if (lvl == 4) { feat = p4; H = 64; }
    else               { feat = p5; H = 32; }
    const int W = H;

    // Normalized box coords (tf.crop_and_resize convention).
    const float ny1 = y1 / (rows - 1.0f);
    const float ny2 = y2 / (rows - 1.0f);
    const float nx1 = x1 / (cols - 1.0f);
    const float nx2 = x2 / (cols - 1.0f);

    // y sample for this block's gy (uniform across the block).
    const float gyf = (float)gy / (float)(EXTENT - 1);
    const float ysv = (ny1 + (ny2 - ny1) * gyf) * (float)(H - 1);
    float y0f = floorf(ysv);
    y0f = fminf(fmaxf(y0f, 0.0f), (float)(H - 2));
    const int   y0 = (int)y0f;
    const float wy = ysv - y0f;

    float* outp = out + (size_t)(box * EXTENT + gy) * EXTENT * CHANNELS;

    #pragma unroll
    for (int t = tid; t < EXTENT * 64; t += 256) {
        const int gx = t >> 6;
        const int c  = (t & 63) << 2;

        const float gxf = (float)gx / (float)(EXTENT - 1);
        const float xsv = (nx1 + (nx2 - nx1) * gxf) * (float)(W - 1);
        float x0f = floorf(xsv);
        x0f = fminf(fmaxf(x0f, 0.0f), (float)(W - 2));
        const int   x0 = (int)x0f;
        const float wx = xsv - x0f;

        const float* base = feat + ((size_t)(y0 * W + x0)) * CHANNELS + c;
        const float4 f00 = *(const float4*)(base);
        const float4 f01 = *(const float4*)(base + CHANNELS);
        const float4 f10 = *(const float4*)(base + (size_t)W * CHANNELS);
        const float4 f11 = *(const float4*)(base + (size_t)W * CHANNELS + CHANNELS);

        const float w00 = (1.0f - wy) * (1.0f - wx);
        const float w01 = (1.0f - wy) * wx;
        const float w10 = wy * (1.0f - wx);
        const float w11 = wy * wx;

        float4 r;
        r.x = f00.x * w00 + f01.x * w01 + f10.x * w10 + f11.x * w11;
        r.y = f00.y * w00 + f01.y * w01 + f10.y * w10 + f11.y * w11;
        r.z = f00.z * w00 + f01.z * w01 + f10.z * w10 + f11.z * w11;
        r.w = f00.w * w00 + f01.w * w01 + f10.w * w10 + f11.w * w11;

        *(float4*)(outp + gx * CHANNELS + c) = r;
    }
}

extern "C" void kernel_launch(void* const* d_in, const int* in_sizes, int n_in,
                              void* d_out, int out_size, void* d_ws, size_t ws_size,
                              hipStream_t stream) {
    const float* metadata = (const float*)d_in[0];
    const float* boxes    = (const float*)d_in[1];
    const float* p2       = (const float*)d_in[2];
    const float* p3       = (const float*)d_in[3];
    const float* p4       = (const float*)d_in[4];
    const float* p5       = (const float*)d_in[5];
    float* out = (float*)d_out;

    const int n_boxes = in_sizes[1] / 4;  // 1024
    dim3 grid(n_boxes * EXTENT);
    dim3 block(256);
    roi_align_pyramid_kernel<<<grid, block, 0, stream>>>(
        metadata, boxes, p2, p3, p4, p5, out);
}

// Round 3
// 142.567 us; speedup vs baseline: 1.0014x; 1.0014x over previous
//
#include <hip/hip_runtime.h>

#define EXTENT 7
#define CHANNELS 256
#define NPTS (EXTENT * EXTENT)  // 49

typedef float v4f __attribute__((ext_vector_type(4)));

// One block per box (grid = n_boxes). 256 threads:
//   lane group (tid & 63) -> 4 channels via v4f (64 lanes x 16B = full 1KB
//   channel row, perfectly coalesced);
//   sub = tid >> 6 in [0,4) -> strided subset of the 49 grid points.
// All taps of a box issue from one CU/XCD -> L1/L2 locality, no cross-XCD
// duplicate fetch for within-box overlap.
__global__ __launch_bounds__(256) void roi_align_pyramid_kernel(
    const float* __restrict__ metadata,
    const float* __restrict__ boxes,
    const float* __restrict__ p2,
    const float* __restrict__ p3,
    const float* __restrict__ p4,
    const float* __restrict__ p5,
    float* __restrict__ out)
{
    const int box = blockIdx.x;
    const int tid = threadIdx.x;
    const int sub = tid >> 6;        // 0..3
    const int c   = (tid & 63) << 2; // channel offset 0,4,...,252

    const float rows = metadata[0];
    const float cols = metadata[1];

    const float x1 = boxes[box * 4 + 0];
    const float y1 = boxes[box * 4 + 1];
    const float x2 = boxes[box * 4 + 2];
    const float y2 = boxes[box * 4 + 3];

    // Level selection — replicate reference fp32 math.
    const float h = y2 - y1;
    const float w = x2 - x1;
    float roi_level = logf(sqrtf(h * w) / sqrtf(rows * cols)) / logf(2.0f);
    roi_level = fminf(5.0f, fmaxf(2.0f, 4.0f + rintf(roi_level)));
    const int lvl = (int)roi_level;  // 2..5

    const float* feat;
    int H;
    if      (lvl == 2) { feat = p2; H = 256; }
    else if (lvl == 3) { feat = p3; H = 128; }
    else if (lvl == 4) { feat = p4; H = 64; }
    else               { feat = p5; H = 32; }
    const int W = H;

    // Normalized box coords (tf.crop_and_resize convention).
    const float ny1 = y1 / (rows - 1.0f);
    const float ny2 = y2 / (rows - 1.0f);
    const float nx1 = x1 / (cols - 1.0f);
    const float nx2 = x2 / (cols - 1.0f);

    float* outp = out + (size_t)box * NPTS * CHANNELS + c;

    auto process = [&](int p) {
        const int gy = p / EXTENT;
        const int gx = p - gy * EXTENT;

        const float gyf = (float)gy / (float)(EXTENT - 1);
        const float ysv = (ny1 + (ny2 - ny1) * gyf) * (float)(H - 1);
        float y0f = floorf(ysv);
        y0f = fminf(fmaxf(y0f, 0.0f), (float)(H - 2));
        const int   y0 = (int)y0f;
        const float wy = ysv - y0f;

        const float gxf = (float)gx / (float)(EXTENT - 1);
        const float xsv = (nx1 + (nx2 - nx1) * gxf) * (float)(W - 1);
        float x0f = floorf(xsv);
        x0f = fminf(fmaxf(x0f, 0.0f), (float)(W - 2));
        const int   x0 = (int)x0f;
        const float wx = xsv - x0f;

        const float* base = feat + ((size_t)(y0 * W + x0)) * CHANNELS + c;
        const v4f f00 = *(const v4f*)(base);
        const v4f f01 = *(const v4f*)(base + CHANNELS);
        const v4f f10 = *(const v4f*)(base + (size_t)W * CHANNELS);
        const v4f f11 = *(const v4f*)(base + (size_t)W * CHANNELS + CHANNELS);

        const float w00 = (1.0f - wy) * (1.0f - wx);
        const float w01 = (1.0f - wy) * wx;
        const float w10 = wy * (1.0f - wx);
        const float w11 = wy * wx;

        v4f r = f00 * w00 + f01 * w01 + f10 * w10 + f11 * w11;

        // Write-once data: bypass L2 so feature lines stay resident.
        __builtin_nontemporal_store(r, (v4f*)(outp + (size_t)p * CHANNELS));
    };

    // 49 points: sub + 4k for k in [0,12) covers p in [0,48); p=48 by sub==0.
    #pragma unroll 4
    for (int k = 0; k < 12; ++k) {
        process(sub + 4 * k);
    }
    if (sub == 0) {
        process(48);
    }
}

extern "C" void kernel_launch(void* const* d_in, const int* in_sizes, int n_in,
                              void* d_out, int out_size, void* d_ws, size_t ws_size,
                              hipStream_t stream) {
    const float* metadata = (const float*)d_in[0];
    const float* boxes    = (const float*)d_in[1];
    const float* p2       = (const float*)d_in[2];
    const float* p3       = (const float*)d_in[3];
    const float* p4       = (const float*)d_in[4];
    const float* p5       = (const float*)d_in[5];
    float* out = (float*)d_out;

    const int n_boxes = in_sizes[1] / 4;  // 1024
    dim3 grid(n_boxes);
    dim3 block(256);
    roi_align_pyramid_kernel<<<grid, block, 0, stream>>>(
        metadata, boxes, p2, p3, p4, p5, out);
}

// Round 4
// 142.462 us; speedup vs baseline: 1.0021x; 1.0007x over previous
//
#include <hip/hip_runtime.h>

#define EXTENT 7
#define CHANNELS 256
#define NPTS (EXTENT * EXTENT)  // 49

typedef float v4f __attribute__((ext_vector_type(4)));

// Grid = 4 * n_boxes. blockIdx = q*n_boxes + box (n_boxes % 8 == 0, so all 4
// sub-blocks of one box land on the same XCD under round-robin dispatch).
// 256 threads: (tid & 63) -> 4 channels via v4f (64 lanes x 16B = full 1KB
// channel row, coalesced); sub16 = q*4 + (tid>>6) in [0,16) -> 3-4 of the 49
// grid points per thread, fully unrolled so ~12-16 loads are in flight.
// Rationale: latency-bound (R2: occupancy 35%, 3.5 TB/s) -> 2x waves/CU.
__global__ __launch_bounds__(256) void roi_align_pyramid_kernel(
    const float* __restrict__ metadata,
    const float* __restrict__ boxes,
    const float* __restrict__ p2,
    const float* __restrict__ p3,
    const float* __restrict__ p4,
    const float* __restrict__ p5,
    float* __restrict__ out,
    int n_boxes)
{
    const int box = blockIdx.x % n_boxes;
    const int q   = blockIdx.x / n_boxes;      // 0..3
    const int tid = threadIdx.x;
    const int sub = (q << 2) | (tid >> 6);     // 0..15
    const int c   = (tid & 63) << 2;           // channel offset

    const float rows = metadata[0];
    const float cols = metadata[1];

    const float x1 = boxes[box * 4 + 0];
    const float y1 = boxes[box * 4 + 1];
    const float x2 = boxes[box * 4 + 2];
    const float y2 = boxes[box * 4 + 3];

    // Level selection — replicate reference fp32 math.
    const float h = y2 - y1;
    const float w = x2 - x1;
    float roi_level = logf(sqrtf(h * w) / sqrtf(rows * cols)) / logf(2.0f);
    roi_level = fminf(5.0f, fmaxf(2.0f, 4.0f + rintf(roi_level)));
    const int lvl = (int)roi_level;  // 2..5

    const float* feat;
    int H;
    if      (lvl == 2) { feat = p2; H = 256; }
    else if (lvl == 3) { feat = p3; H = 128; }
    else if (lvl == 4) { feat = p4; H = 64; }
    else               { feat = p5; H = 32; }
    const int W = H;

    // Normalized box coords (tf.crop_and_resize convention).
    const float ny1 = y1 / (rows - 1.0f);
    const float ny2 = y2 / (rows - 1.0f);
    const float nx1 = x1 / (cols - 1.0f);
    const float nx2 = x2 / (cols - 1.0f);

    float* outp = out + (size_t)box * NPTS * CHANNELS + c;

    auto process = [&](int p) {
        const int gy = p / EXTENT;
        const int gx = p - gy * EXTENT;

        const float gyf = (float)gy / (float)(EXTENT - 1);
        const float ysv = (ny1 + (ny2 - ny1) * gyf) * (float)(H - 1);
        float y0f = floorf(ysv);
        y0f = fminf(fmaxf(y0f, 0.0f), (float)(H - 2));
        const int   y0 = (int)y0f;
        const float wy = ysv - y0f;

        const float gxf = (float)gx / (float)(EXTENT - 1);
        const float xsv = (nx1 + (nx2 - nx1) * gxf) * (float)(W - 1);
        float x0f = floorf(xsv);
        x0f = fminf(fmaxf(x0f, 0.0f), (float)(W - 2));
        const int   x0 = (int)x0f;
        const float wx = xsv - x0f;

        const float* base = feat + ((size_t)(y0 * W + x0)) * CHANNELS + c;
        const v4f f00 = *(const v4f*)(base);
        const v4f f01 = *(const v4f*)(base + CHANNELS);
        const v4f f10 = *(const v4f*)(base + (size_t)W * CHANNELS);
        const v4f f11 = *(const v4f*)(base + (size_t)W * CHANNELS + CHANNELS);

        const float w00 = (1.0f - wy) * (1.0f - wx);
        const float w01 = (1.0f - wy) * wx;
        const float w10 = wy * (1.0f - wx);
        const float w11 = wy * wx;

        v4f r = f00 * w00 + f01 * w01 + f10 * w10 + f11 * w11;

        // Write-once data: bypass caches so feature lines stay resident.
        __builtin_nontemporal_store(r, (v4f*)(outp + (size_t)p * CHANNELS));
    };

    // 49 points: sub + 16k for k in [0,3) covers p in [0,48); p=48 by sub==0.
    #pragma unroll
    for (int k = 0; k < 3; ++k) {
        process(sub + 16 * k);
    }
    if (sub == 0) {
        process(48);
    }
}

extern "C" void kernel_launch(void* const* d_in, const int* in_sizes, int n_in,
                              void* d_out, int out_size, void* d_ws, size_t ws_size,
                              hipStream_t stream) {
    const float* metadata = (const float*)d_in[0];
    const float* boxes    = (const float*)d_in[1];
    const float* p2       = (const float*)d_in[2];
    const float* p3       = (const float*)d_in[3];
    const float* p4       = (const float*)d_in[4];
    const float* p5       = (const float*)d_in[5];
    float* out = (float*)d_out;

    const int n_boxes = in_sizes[1] / 4;  // 1024
    dim3 grid(n_boxes * 4);
    dim3 block(256);
    roi_align_pyramid_kernel<<<grid, block, 0, stream>>>(
        metadata, boxes, p2, p3, p4, p5, out, n_boxes);
}